// Round 1
// baseline (438.510 us; speedup 1.0000x reference)
//
#include <hip/hip_runtime.h>
#include <math.h>

#define NROWS (8 * 2048 * 16)   // B*S*G = 262144 rows, each D=64
#define D 64
#define K 320
#define G 16
#define CHUNK 32
#define NCHUNK (K / CHUNK)      // 10
#define BLOCK 128

__global__ __launch_bounds__(BLOCK) void vq_kernel(
    const float* __restrict__ inputs,      // [B,S,H] = [NROWS, 64]
    const int* __restrict__ mask,          // [B,S] as int32
    const float* __restrict__ Wcb,         // [64, 320]
    const float* __restrict__ bcb,         // [320]
    const float* __restrict__ codevec,     // [320, 64]
    float* __restrict__ out_cv,            // [NROWS, 64]
    float* __restrict__ out_cw)            // [NROWS] (codewords as float)
{
    // x staged transposed: xs[d][row_in_block]; read xs[d][tid] is conflict-free
    __shared__ float xs[D][BLOCK];
    const int tid = threadIdx.x;
    const long long row0 = (long long)blockIdx.x * BLOCK;

    // Cooperative stage: BLOCK rows x 64 floats, contiguous region
    {
        const float4* in4 = reinterpret_cast<const float4*>(inputs + row0 * D);
        #pragma unroll
        for (int i = 0; i < 16; ++i) {          // 2048 float4 / 128 threads
            int idx = tid + i * BLOCK;
            float4 v = in4[idx];
            int f = idx * 4;
            int r = f >> 6;                      // row in block
            int d = f & 63;                      // d (multiple of 4)
            xs[d + 0][r] = v.x;
            xs[d + 1][r] = v.y;
            xs[d + 2][r] = v.z;
            xs[d + 3][r] = v.w;
        }
    }
    __syncthreads();

    float cvacc[D];
    #pragma unroll
    for (int d = 0; d < D; ++d) cvacc[d] = 0.0f;
    float m = -INFINITY;   // running max
    float sum = 0.0f;      // running exp-sum (relative to m)
    int amax = 0;          // running argmax (first-index tie-break)

    #pragma unroll 1
    for (int kc = 0; kc < NCHUNK; ++kc) {
        const int k0 = kc * CHUNK;

        // ---- logits chunk: l[j] = b[k0+j] + sum_d x[d]*W[d][k0+j] ----
        float l[CHUNK];
        #pragma unroll
        for (int j = 0; j < CHUNK; ++j) l[j] = bcb[k0 + j];   // uniform -> s_load
        #pragma unroll 2
        for (int d = 0; d < D; ++d) {
            const float xd = xs[d][tid];                       // per-lane, bank-free
            const float* wrow = &Wcb[d * K + k0];              // uniform -> s_load
            #pragma unroll
            for (int j = 0; j < CHUNK; ++j) l[j] = fmaf(xd, wrow[j], l[j]);
        }

        // ---- chunk max, first index wins on ties ----
        float cm = l[0]; int ci = 0;
        #pragma unroll
        for (int j = 1; j < CHUNK; ++j) { if (l[j] > cm) { cm = l[j]; ci = j; } }

        // ---- online-softmax rescale (at most once per chunk) ----
        if (cm > m) {
            const float sc = __expf(m - cm);   // first chunk: exp(-inf) = 0
            sum *= sc;
            #pragma unroll
            for (int d = 0; d < D; ++d) cvacc[d] *= sc;
            m = cm;
            amax = k0 + ci;                    // strict > keeps earliest max
        }

        // ---- accumulate probs * codevectors ----
        for (int j = 0; j < CHUNK; ++j) {
            const float p = __expf(l[j] - m);
            sum += p;
            const float* cvr = &codevec[(k0 + j) * D];         // uniform -> s_load
            #pragma unroll
            for (int d = 0; d < D; ++d) cvacc[d] = fmaf(p, cvr[d], cvacc[d]);
        }
    }

    const long long row = row0 + tid;
    const int mk = mask[row / G];
    const float inv = mk ? (1.0f / sum) : 0.0f;

    float4* o4 = reinterpret_cast<float4*>(out_cv + row * D);
    #pragma unroll
    for (int d = 0; d < D; d += 4) {
        float4 v;
        v.x = cvacc[d + 0] * inv;
        v.y = cvacc[d + 1] * inv;
        v.z = cvacc[d + 2] * inv;
        v.w = cvacc[d + 3] * inv;
        o4[d >> 2] = v;
    }
    out_cw[row] = mk ? (float)amax : 0.0f;
}

extern "C" void kernel_launch(void* const* d_in, const int* in_sizes, int n_in,
                              void* d_out, int out_size, void* d_ws, size_t ws_size,
                              hipStream_t stream) {
    const float* inputs  = (const float*)d_in[0];
    const int*   mask    = (const int*)d_in[1];
    const float* Wcb     = (const float*)d_in[2];
    const float* bcb     = (const float*)d_in[3];
    const float* codevec = (const float*)d_in[4];

    float* out_cv = (float*)d_out;
    float* out_cw = out_cv + (size_t)NROWS * D;

    vq_kernel<<<NROWS / BLOCK, BLOCK, 0, stream>>>(
        inputs, mask, Wcb, bcb, codevec, out_cv, out_cw);
}

// Round 3
// 104.881 us; speedup vs baseline: 4.1810x; 4.1810x over previous
//
#include <hip/hip_runtime.h>
#include <math.h>

typedef _Float16 f16;
typedef _Float16 f16x8 __attribute__((ext_vector_type(8)));
typedef _Float16 f16x4 __attribute__((ext_vector_type(4)));
typedef float f32x4 __attribute__((ext_vector_type(4)));

#define NROWS (8 * 2048 * 16)   // B*S*G rows of D=64
#define BLOCK 512
#define WAVES 8
#define NITER 4                 // 16-row groups per wave
#define NT 20                   // 320/16 code tiles
#define GRID 512                // 512*8 waves * 4 iters * 16 rows = 262144
#define TAU 4e-3f               // rescue threshold >> logit err (~1e-4)

__global__ __launch_bounds__(BLOCK) void vq_mfma(
    const float* __restrict__ inputs,   // [262144][64]
    const int* __restrict__ mask,       // [16384]
    const float* __restrict__ Wcb,      // [64][320]
    const float* __restrict__ bcb,      // [320]
    const float* __restrict__ codevec,  // [320][64]
    float* __restrict__ out_cv,         // [262144][64]
    float* __restrict__ out_cw)         // [262144] as float
{
    // W^T f16, swizzled: row n, d in 8 slots of 8, slot' = slot^(n&7)
    __shared__ __align__(16) f16 Wh[320 * 64];
    // CV^T f16: row d, k in 40 slots; low-3 slot bits ^ (d&7)
    __shared__ __align__(16) f16 CVt[64 * 320];
    __shared__ __align__(16) float bs[320];
    // P transpose scratch: per wave, 2 slots x 16 rows x 40 f16 (80B padded rows)
    __shared__ __align__(16) f16 Pb[WAVES][2][640];

    const int tid = threadIdx.x;

    for (int e = tid; e < 64 * 320; e += BLOCK) {
        int d = e / 320, n = e - d * 320;
        int s = d >> 3;
        Wh[n * 64 + (((s ^ n) & 7) << 3) + (d & 7)] = (f16)Wcb[e];
    }
    for (int e = tid; e < 320 * 64; e += BLOCK) {
        int k = e >> 6, d = e & 63;
        int s = k >> 3;
        int sw = (s & 0x38) | ((s ^ d) & 7);
        CVt[d * 320 + (sw << 3) + (k & 7)] = (f16)codevec[e];
    }
    for (int e = tid; e < 320; e += BLOCK) bs[e] = bcb[e];
    __syncthreads();

    const int wid = tid >> 6;
    const int lane = tid & 63;
    const int l15 = lane & 15;          // row within group / C column
    const int lg = lane >> 4;           // k-quarter 0..3
    const int u = blockIdx.x * WAVES + wid;   // 0..4095
    f16* pw0 = &Pb[wid][0][0];
    f16* pw1 = &Pb[wid][1][0];

    for (int it = 0; it < NITER; ++it) {
        const int row0 = u * (NITER * 16) + it * 16;
        const float* xrow = inputs + (size_t)(row0 + l15) * 64;

        // ---- x B-frags, 2 unscaled f16 limbs ----
        f16x8 xh[2], xl[2];
        #pragma unroll
        for (int kc = 0; kc < 2; ++kc) {
            float4 a = *(const float4*)(xrow + kc * 32 + lg * 8);
            float4 b = *(const float4*)(xrow + kc * 32 + lg * 8 + 4);
            float xv[8] = {a.x, a.y, a.z, a.w, b.x, b.y, b.z, b.w};
            f16x8 h, l;
            #pragma unroll
            for (int e = 0; e < 8; ++e) {
                f16 hh = (f16)xv[e];
                h[e] = hh;
                l[e] = (f16)(xv[e] - (float)hh);
            }
            xh[kc] = h;
            xl[kc] = l;
        }

        // ---- logits S^T = Wh^T * (xh + xl) ----
        f32x4 acc[NT];
        #pragma unroll
        for (int t = 0; t < NT; ++t) acc[t] = (f32x4){0.f, 0.f, 0.f, 0.f};
        #pragma unroll
        for (int kc = 0; kc < 2; ++kc) {
            #pragma unroll
            for (int nt = 0; nt < NT; ++nt) {
                int n = nt * 16 + l15;
                int base = n * 64 + ((((kc * 4 + lg) ^ n) & 7) << 3);
                f16x8 whf = *(const f16x8*)&Wh[base];
                acc[nt] = __builtin_amdgcn_mfma_f32_16x16x32_f16(whf, xl[kc], acc[nt], 0, 0, 0);
                acc[nt] = __builtin_amdgcn_mfma_f32_16x16x32_f16(whf, xh[kc], acc[nt], 0, 0, 0);
            }
        }

        // ---- bias + top-2 max / argmax (first-index tie-break) ----
        float m1 = -INFINITY, m2 = -INFINITY;
        int i1 = 0;
        #pragma unroll
        for (int nt = 0; nt < NT; ++nt) {
            f32x4 b4 = *(const f32x4*)&bs[nt * 16 + lg * 4];
            acc[nt] += b4;
            #pragma unroll
            for (int r = 0; r < 4; ++r) {
                float v = acc[nt][r];
                m2 = fmaxf(m2, fminf(m1, v));          // old m1 competes for slot 2
                if (v > m1) { m1 = v; i1 = nt * 16 + lg * 4 + r; }
            }
        }
        #pragma unroll
        for (int dx = 16; dx <= 32; dx <<= 1) {
            float mo = __shfl_xor(m1, dx, 64);
            int io = __shfl_xor(i1, dx, 64);
            float m2o = __shfl_xor(m2, dx, 64);
            m2 = fmaxf(fmaxf(m2, m2o), fminf(m1, mo));
            if (mo > m1 || (mo == m1 && io < i1)) { m1 = mo; i1 = io; }
        }

        // ---- exact-argmax rescue for near-ties (uses logits still in acc) ----
        const int mk = mask[u * NITER + it];   // wave-uniform (16 groups = one (b,s))
        int cw = i1;
        const bool flag = mk && (m1 - m2 < TAU);
        if (__any(flag)) {
            const float thr = m1 - TAU;
            int c0 = -1, c1 = -1, c2 = -1;
            if (flag) {
                #pragma unroll
                for (int nt = 0; nt < NT; ++nt) {
                    #pragma unroll
                    for (int r = 0; r < 4; ++r) {
                        if (acc[nt][r] >= thr) {
                            int c = nt * 16 + lg * 4 + r;
                            if (c0 < 0) c0 = c;
                            else if (c1 < 0) c1 = c;
                            else if (c2 < 0) c2 = c;
                        }
                    }
                }
            }
            float bv = -INFINITY;
            int bi = 0x7fffffff;
            #pragma unroll 1
            for (int t = 0; t < 3; ++t) {
                int c = (t == 0) ? c0 : ((t == 1) ? c1 : c2);
                if (__any(c >= 0)) {
                    if (c >= 0) {
                        // exact f32, sequential d — same error class as the
                        // round-1 kernel that matched np argmax with 0 flips
                        float sacc = bs[c];
                        #pragma unroll 8
                        for (int d = 0; d < 64; ++d)
                            sacc = fmaf(xrow[d], Wcb[d * 320 + c], sacc);
                        if (sacc > bv || (sacc == bv && c < bi)) { bv = sacc; bi = c; }
                    }
                }
            }
            #pragma unroll
            for (int dx = 16; dx <= 32; dx <<= 1) {
                float vo = __shfl_xor(bv, dx, 64);
                int io = __shfl_xor(bi, dx, 64);
                if (vo > bv || (vo == bv && io < bi)) { bv = vo; bi = io; }
            }
            if (flag) cw = bi;
        }

        // ---- exp + row sum (probs overwrite acc) ----
        float sum = 0.f;
        #pragma unroll
        for (int nt = 0; nt < NT; ++nt) {
            #pragma unroll
            for (int r = 0; r < 4; ++r) {
                float p = __expf(acc[nt][r] - m1);
                acc[nt][r] = p;
                sum += p;
            }
        }
        sum += __shfl_xor(sum, 16, 64);
        sum += __shfl_xor(sum, 32, 64);

        // ---- PV: cv^T = CV^T * P^T, double-buffered LDS transpose ----
        f32x4 cv[4];
        #pragma unroll
        for (int dt = 0; dt < 4; ++dt) cv[dt] = (f32x4){0.f, 0.f, 0.f, 0.f};

        // prologue: stage P chunk 0
        {
            #pragma unroll
            for (int nt2 = 0; nt2 < 2; ++nt2) {
                f16x4 pk;
                #pragma unroll
                for (int r = 0; r < 4; ++r) pk[r] = (f16)acc[nt2][r];
                int off = l15 * 40 + ((nt2 * 2 + (lg >> 1)) << 3) + ((lg & 1) << 2);
                *(f16x4*)&pw0[off] = pk;
            }
        }
        #pragma unroll
        for (int kc = 0; kc < 10; ++kc) {
            asm volatile("s_waitcnt lgkmcnt(0)" ::: "memory");
            __builtin_amdgcn_sched_barrier(0);
            f16* rp = (kc & 1) ? pw1 : pw0;
            f16x8 pf = *(const f16x8*)&rp[l15 * 40 + lg * 8];
            if (kc < 9) {   // stage next chunk into the other slot
                f16* wp = (kc & 1) ? pw0 : pw1;
                #pragma unroll
                for (int nt2 = 0; nt2 < 2; ++nt2) {
                    f16x4 pk;
                    #pragma unroll
                    for (int r = 0; r < 4; ++r) pk[r] = (f16)acc[(kc + 1) * 2 + nt2][r];
                    int off = l15 * 40 + ((nt2 * 2 + (lg >> 1)) << 3) + ((lg & 1) << 2);
                    *(f16x4*)&wp[off] = pk;
                }
            }
            #pragma unroll
            for (int dt = 0; dt < 4; ++dt) {
                int d = dt * 16 + l15;
                int s = kc * 4 + lg;
                int sw = (s & 0x38) | ((s ^ d) & 7);
                f16x8 cf = *(const f16x8*)&CVt[d * 320 + (sw << 3)];
                cv[dt] = __builtin_amdgcn_mfma_f32_16x16x32_f16(cf, pf, cv[dt], 0, 0, 0);
            }
        }

        // ---- epilogue ----
        const float inv = mk ? (1.0f / sum) : 0.0f;
        float* orow = out_cv + (size_t)(row0 + l15) * 64;
        #pragma unroll
        for (int dt = 0; dt < 4; ++dt) {
            f32x4 v;
            v[0] = cv[dt][0] * inv;
            v[1] = cv[dt][1] * inv;
            v[2] = cv[dt][2] * inv;
            v[3] = cv[dt][3] * inv;
            *(f32x4*)(orow + dt * 16 + lg * 4) = v;
        }
        if (lg == 0) out_cw[row0 + l15] = mk ? (float)cw : 0.0f;
    }
}

extern "C" void kernel_launch(void* const* d_in, const int* in_sizes, int n_in,
                              void* d_out, int out_size, void* d_ws, size_t ws_size,
                              hipStream_t stream) {
    const float* inputs  = (const float*)d_in[0];
    const int*   mask    = (const int*)d_in[1];
    const float* Wcb     = (const float*)d_in[2];
    const float* bcb     = (const float*)d_in[3];
    const float* codevec = (const float*)d_in[4];

    float* out_cv = (float*)d_out;
    float* out_cw = out_cv + (size_t)NROWS * 64;

    vq_mfma<<<GRID, BLOCK, 0, stream>>>(inputs, mask, Wcb, bcb, codevec, out_cv, out_cw);
}